// Round 10
// baseline (155.310 us; speedup 1.0000x reference)
//
#include <hip/hip_runtime.h>

typedef __attribute__((ext_vector_type(4))) float f32x4;

#define NT 256
#define S 10
#define D 100
#define H 16
#define NITER 5
#define RQ 25   // LDS out-staging row stride in quads (24 used + 1 pad)
#define OUTQ 24 // quads per output row (6*16 floats)

// Weights/biases are read DIRECTLY from global at wave-uniform addresses:
// the compiler emits s_load through the scalar/constant cache, weights live
// in SGPRs, and v_fma takes the SGPR operand directly. This removes
// (a) the 4.2 GB aggregate LDS weight traffic that made r9's proj kernel
//     LDS-throughput-bound (~400 ds_read_b128/thread), and
// (b) the VGPR promotion balloon (LDS reads -> VGPRs) that caused the
//     scratch-spill signature in rounds 1-8 (WRITE_SIZE 150-550 MB).
#define WQ(base, d, q) (*(const f32x4*)&(base)[(d) * H + (q) * 4])

__global__ __launch_bounds__(NT, 1)
void attn_greedy_kernel(const float* __restrict__ user_intent,
                        const float* __restrict__ item_corpus,
                        const float* __restrict__ W_proj,
                        const float* __restrict__ b_proj,
                        const float* __restrict__ W_k,
                        const float* __restrict__ b_k,
                        float* __restrict__ out)
{
    __shared__ f32x4 s_out[NT * RQ];  // 100 KB out staging (only LDS use)

    const int t = threadIdx.x;
    const size_t b = (size_t)blockIdx.x * NT + t;   // one row per thread
    const f32x4* crow = (const f32x4*)item_corpus + b * (S * D / 4);

    // biases: uniform -> SGPRs
    f32x4 bp[4], bk[4];
    #pragma unroll
    for (int q = 0; q < 4; ++q) {
        bp[q] = *(const f32x4*)&b_proj[q * 4];
        bk[q] = *(const f32x4*)&b_k[q * 4];
    }

    // user_intent: one full 64B line per lane; stash in s_out row 0..3 now.
    const f32x4* urow = (const f32x4*)user_intent + b * 4;
    f32x4 usum[4];
    #pragma unroll
    for (int q = 0; q < 4; ++q) {
        f32x4 u = urow[q];
        usum[q] = u;
        s_out[t * RQ + q] = u;
    }

    // ---- Projection: s OUTER, i INNER -> each lane streams its row
    // sequentially. Weights via scalar loads (uniform), corpus via
    // per-lane float4 loads. Same d-ascending accumulation order as all
    // passing rounds -> bit-identical.
    f32x4 ic[S][4];
    #pragma unroll
    for (int s = 0; s < S; ++s) {
        f32x4 a0 = bp[0], a1 = bp[1], a2 = bp[2], a3 = bp[3];
        #pragma unroll 5
        for (int i = 0; i < D / 4; ++i) {
            f32x4 c = crow[s * (D / 4) + i];
            #pragma unroll
            for (int dd = 0; dd < 4; ++dd) {
                float a = c[dd];
                const int d = i * 4 + dd;
                a0 += a * WQ(W_proj, d, 0);
                a1 += a * WQ(W_proj, d, 1);
                a2 += a * WQ(W_proj, d, 2);
                a3 += a * WQ(W_proj, d, 3);
            }
        }
        ic[s][0] = a0; ic[s][1] = a1; ic[s][2] = a2; ic[s][3] = a3;
    }

    // ---- Greedy iterations (rolled: one body copy; W_k re-read per it
    // from K$ -> cheap scalar loads, no register-file residency required).
    #pragma unroll 1
    for (int it = 0; it < NITER; ++it) {
        // ic = ic @ Wk + bk, per-s IN PLACE, k ascending (bit-identical).
        #pragma unroll
        for (int s = 0; s < S; ++s) {
            f32x4 n0 = bk[0], n1 = bk[1], n2 = bk[2], n3 = bk[3];
            #pragma unroll
            for (int k = 0; k < H; ++k) {
                float a = ic[s][k >> 2][k & 3];
                n0 += a * WQ(W_k, k, 0);
                n1 += a * WQ(W_k, k, 1);
                n2 += a * WQ(W_k, k, 2);
                n3 += a * WQ(W_k, k, 3);
            }
            ic[s][0] = n0; ic[s][1] = n1; ic[s][2] = n2; ic[s][3] = n3;
        }

        // src = mean(ui)
        float cnt = (float)(it + 1);
        f32x4 src[4];
        #pragma unroll
        for (int q = 0; q < 4; ++q) src[q] = usum[q] / cnt;

        // scores + first-max argmax (softmax skipped: monotonic)
        float best = 0.0f;
        int bidx = 0;
        #pragma unroll
        for (int s = 0; s < S; ++s) {
            float sc = 0.0f;
            #pragma unroll
            for (int q = 0; q < 4; ++q)
                #pragma unroll
                for (int c = 0; c < 4; ++c)
                    sc += ic[s][q][c] * src[q][c];
            if (s == 0 || sc > best) { best = sc; bidx = s; }
        }

        // item_vec = ic[bidx] via unrolled select (static register indexing)
        f32x4 iv[4];
        #pragma unroll
        for (int q = 0; q < 4; ++q) iv[q] = ic[0][q];
        #pragma unroll
        for (int s = 1; s < S; ++s) {
            bool take = (bidx == s);
            #pragma unroll
            for (int q = 0; q < 4; ++q)
                iv[q] = take ? ic[s][q] : iv[q];
        }

        #pragma unroll
        for (int q = 0; q < 4; ++q) {
            usum[q] += iv[q];
            s_out[t * RQ + (it + 1) * 4 + q] = iv[q];
        }
    }

    // ---- Coalesced output: block region is contiguous 96 KB; lanes store
    // consecutive 16B -> full-line writes only.
    __syncthreads();
    f32x4* out4 = (f32x4*)out;
    const size_t obase = (size_t)blockIdx.x * NT * OUTQ;
    #pragma unroll
    for (int k = 0; k < OUTQ; ++k) {
        int j = t + k * NT;
        int row = j / OUTQ;
        int q = j - row * OUTQ;
        out4[obase + j] = s_out[row * RQ + q];
    }
}

extern "C" void kernel_launch(void* const* d_in, const int* in_sizes, int n_in,
                              void* d_out, int out_size, void* d_ws, size_t ws_size,
                              hipStream_t stream) {
    const float* user_intent = (const float*)d_in[0];
    const float* item_corpus = (const float*)d_in[1];
    const float* W_proj      = (const float*)d_in[2];
    const float* b_proj      = (const float*)d_in[3];
    const float* W_k         = (const float*)d_in[4];
    const float* b_k         = (const float*)d_in[5];
    float* out = (float*)d_out;

    const int bs = 65536;
    hipLaunchKernelGGL(attn_greedy_kernel,
                       dim3(bs / NT), dim3(NT), 0, stream,
                       user_intent, item_corpus, W_proj, b_proj, W_k, b_k, out);
}

// Round 11
// 112.893 us; speedup vs baseline: 1.3757x; 1.3757x over previous
//
#include <hip/hip_runtime.h>

typedef __attribute__((ext_vector_type(4))) float f32x4;

#define NT 256
#define S 10
#define D 100
#define H 16
#define NITER 5
#define LPR 4               // lanes cooperating on one batch row
#define RPB (NT / LPR)      // 64 batch rows per block
#define RQ 25               // out-staging row stride in quads (24 used + 1 pad)
#define OUTQ 24             // quads per output row (6*16 floats)

// Weights/biases read DIRECTLY from global at wave-uniform addresses ->
// s_load through the scalar/constant cache, SGPR operands into v_fma.
// No LDS weight tile => no VGPR promotion balloon => no spill (r10 proof:
// WRITE_SIZE collapsed to exactly the 25 MB output).
#define WQ(base, d, q) (*(const f32x4*)&(base)[(d) * H + (q) * 4])

__global__ __launch_bounds__(NT, 1)
void attn_greedy_kernel(const float* __restrict__ user_intent,
                        const float* __restrict__ item_corpus,
                        const float* __restrict__ W_proj,
                        const float* __restrict__ b_proj,
                        const float* __restrict__ W_k,
                        const float* __restrict__ b_k,
                        float* __restrict__ out)
{
    __shared__ f32x4 s_out[RPB * RQ];      // 25.6 KB out staging (only LDS)

    const int t = threadIdx.x;
    const int quarter = t & 3;             // lane within the 4-lane row group
    const int r = t >> 2;                  // batch row within block
    const size_t b = (size_t)blockIdx.x * RPB + r;
    // rows per lane: {3,3,2,2}; global s start: {0,3,6,8}
    const bool has3 = (quarter < 2);
    const int sbase = has3 ? quarter * 3 : 2 + quarter * 2;

    const f32x4* crow = (const f32x4*)item_corpus + b * (S * D / 4) + sbase * (D / 4);

    // biases: uniform -> SGPRs
    f32x4 bp[4], bk[4];
    #pragma unroll
    for (int q = 0; q < 4; ++q) {
        bp[q] = *(const f32x4*)&b_proj[q * 4];
        bk[q] = *(const f32x4*)&b_k[q * 4];
    }

    // user_intent: all 4 lanes hold the row (same cache line; broadcast).
    const f32x4* urow = (const f32x4*)user_intent + b * 4;
    f32x4 usum[4];
    #pragma unroll
    for (int q = 0; q < 4; ++q) {
        usum[q] = urow[q];
        if (quarter == 0) s_out[r * RQ + q] = usum[q];   // ui[:,0,:]
    }

    // ---- Projection of this lane's 2-3 rows (each streamed sequentially,
    // d-ascending accumulation order -> bit-identical to all passing rounds).
    f32x4 ic[3][4];
    #pragma unroll
    for (int ls = 0; ls < 3; ++ls) {
        if (ls < 2 || has3) {
            f32x4 a0 = bp[0], a1 = bp[1], a2 = bp[2], a3 = bp[3];
            #pragma unroll 5
            for (int i = 0; i < D / 4; ++i) {
                f32x4 c = crow[ls * (D / 4) + i];
                #pragma unroll
                for (int dd = 0; dd < 4; ++dd) {
                    float a = c[dd];
                    const int d = i * 4 + dd;
                    a0 += a * WQ(W_proj, d, 0);
                    a1 += a * WQ(W_proj, d, 1);
                    a2 += a * WQ(W_proj, d, 2);
                    a3 += a * WQ(W_proj, d, 3);
                }
            }
            ic[ls][0] = a0; ic[ls][1] = a1; ic[ls][2] = a2; ic[ls][3] = a3;
        }
    }

    // ---- Greedy iterations (rolled; W_k re-read per it from K$ -> cheap)
    #pragma unroll 1
    for (int it = 0; it < NITER; ++it) {
        // ic = ic @ Wk + bk, in place per local row (k ascending)
        #pragma unroll
        for (int ls = 0; ls < 3; ++ls) {
            if (ls < 2 || has3) {
                f32x4 n0 = bk[0], n1 = bk[1], n2 = bk[2], n3 = bk[3];
                #pragma unroll
                for (int k = 0; k < H; ++k) {
                    float a = ic[ls][k >> 2][k & 3];
                    n0 += a * WQ(W_k, k, 0);
                    n1 += a * WQ(W_k, k, 1);
                    n2 += a * WQ(W_k, k, 2);
                    n3 += a * WQ(W_k, k, 3);
                }
                ic[ls][0] = n0; ic[ls][1] = n1; ic[ls][2] = n2; ic[ls][3] = n3;
            }
        }

        // src = mean(ui); usum is bit-identical in all 4 lanes
        float cnt = (float)(it + 1);
        f32x4 src[4];
        #pragma unroll
        for (int q = 0; q < 4; ++q) src[q] = usum[q] / cnt;

        // local scores + first-max argmax (global s index)
        float best = -__builtin_inff();
        int gidx = sbase;
        #pragma unroll
        for (int ls = 0; ls < 3; ++ls) {
            if (ls < 2 || has3) {
                float sc = 0.0f;
                #pragma unroll
                for (int q = 0; q < 4; ++q)
                    #pragma unroll
                    for (int c = 0; c < 4; ++c)
                        sc += ic[ls][q][c] * src[q][c];
                if (sc > best) { best = sc; gidx = sbase + ls; }
            }
        }

        // combine across the 4-lane group: lexicographic (score, -idx)
        // == global first-max (each score computed exactly once)
        #pragma unroll
        for (int off = 1; off <= 2; off <<= 1) {
            float osc = __shfl_xor(best, off);
            int oidx = __shfl_xor(gidx, off);
            if (osc > best || (osc == best && oidx < gidx)) { best = osc; gidx = oidx; }
        }

        // item_vec: owner lane selects (static indexing), others zero,
        // 2-round xor-shuffle sum broadcasts exactly (x+0+0+0)
        f32x4 iv[4];
        #pragma unroll
        for (int q = 0; q < 4; ++q) iv[q] = f32x4{0.f, 0.f, 0.f, 0.f};
        #pragma unroll
        for (int ls = 0; ls < 3; ++ls) {
            if (ls < 2 || has3) {
                bool take = ((sbase + ls) == gidx);
                #pragma unroll
                for (int q = 0; q < 4; ++q)
                    iv[q] = take ? ic[ls][q] : iv[q];
            }
        }
        #pragma unroll
        for (int off = 1; off <= 2; off <<= 1)
            #pragma unroll
            for (int q = 0; q < 4; ++q)
                #pragma unroll
                for (int c = 0; c < 4; ++c)
                    iv[q][c] += __shfl_xor(iv[q][c], off);

        #pragma unroll
        for (int q = 0; q < 4; ++q) {
            usum[q] += iv[q];
            if (quarter == 0) s_out[r * RQ + (it + 1) * 4 + q] = iv[q];
        }
    }

    // ---- Coalesced output: 64 rows x 24 quads = contiguous 24 KB per block.
    __syncthreads();
    f32x4* out4 = (f32x4*)out;
    const size_t obase = (size_t)blockIdx.x * RPB * OUTQ;
    #pragma unroll
    for (int k = 0; k < (RPB * OUTQ) / NT; ++k) {   // 6 iterations
        int j = t + k * NT;
        int row = j / OUTQ;
        int q = j - row * OUTQ;
        out4[obase + j] = s_out[row * RQ + q];
    }
}

extern "C" void kernel_launch(void* const* d_in, const int* in_sizes, int n_in,
                              void* d_out, int out_size, void* d_ws, size_t ws_size,
                              hipStream_t stream) {
    const float* user_intent = (const float*)d_in[0];
    const float* item_corpus = (const float*)d_in[1];
    const float* W_proj      = (const float*)d_in[2];
    const float* b_proj      = (const float*)d_in[3];
    const float* W_k         = (const float*)d_in[4];
    const float* b_k         = (const float*)d_in[5];
    float* out = (float*)d_out;

    const int bs = 65536;
    hipLaunchKernelGGL(attn_greedy_kernel,
                       dim3(bs / RPB), dim3(NT), 0, stream,
                       user_intent, item_corpus, W_proj, b_proj, W_k, b_k, out);
}